// Round 3
// baseline (192.585 us; speedup 1.0000x reference)
//
#include <hip/hip_runtime.h>
#include <hip/hip_bf16.h>
#include <math.h>

#define D_DIM 512
#define TILE  128
#define BK    64

typedef float f32x4 __attribute__((ext_vector_type(4)));
typedef unsigned long long u64;

// ---- helpers ---------------------------------------------------------------

__device__ inline unsigned int fkey(float f) {
    unsigned int u = __float_as_uint(f);
    return (u & 0x80000000u) ? ~u : (u | 0x80000000u);
}

__device__ inline u64 shfl_xor_u64(u64 x, int m) {
    int lo = __shfl_xor((int)(unsigned)(x & 0xFFFFFFFFull), m, 64);
    int hi = __shfl_xor((int)(unsigned)(x >> 32), m, 64);
    return ((u64)(unsigned)hi << 32) | (u64)(unsigned)lo;
}

__device__ inline void async16(unsigned char* lds, const unsigned char* g) {
    __builtin_amdgcn_global_load_lds(
        (const __attribute__((address_space(1))) void*)g,
        (__attribute__((address_space(3))) void*)lds,
        16, 0, 0);
}

// ---- kernel 1: row L2-normalize -> fp8 e4m3 (x8 scale), init best/acc/cnt --

__global__ __launch_bounds__(256) void normalize_rows(
        const float* __restrict__ in, unsigned char* __restrict__ xb,
        float* __restrict__ inv_norm, u64* __restrict__ best,
        float* __restrict__ acc, int* __restrict__ cnt) {
    const int row  = blockIdx.x * 4 + (threadIdx.x >> 6);
    const int lane = threadIdx.x & 63;
    if (blockIdx.x == 0 && threadIdx.x == 0) { acc[0] = 0.f; cnt[0] = 0; }
    const float4* rp = (const float4*)(in + (size_t)row * D_DIM) + lane * 2;
    float4 a = rp[0], b = rp[1];
    float s = a.x*a.x + a.y*a.y + a.z*a.z + a.w*a.w
            + b.x*b.x + b.y*b.y + b.z*b.z + b.w*b.w;
    #pragma unroll
    for (int m = 1; m <= 32; m <<= 1) s += __shfl_xor(s, m, 64);
    float inv = 1.0f / fmaxf(sqrtf(s), 1e-8f);
    if (lane == 0) {
        inv_norm[row] = inv;
        best[row] = 0ull;   // below any real packed key
    }
    float sc = inv * 8.0f;  // x8: dots scale by 64 (monotone), avoids subnormals
    int lo = __builtin_amdgcn_cvt_pk_fp8_f32(a.x*sc, a.y*sc, 0, false);
    lo     = __builtin_amdgcn_cvt_pk_fp8_f32(a.z*sc, a.w*sc, lo, true);
    int hi = __builtin_amdgcn_cvt_pk_fp8_f32(b.x*sc, b.y*sc, 0, false);
    hi     = __builtin_amdgcn_cvt_pk_fp8_f32(b.z*sc, b.w*sc, hi, true);
    ((int2*)(xb + (size_t)row * D_DIM))[lane] = make_int2(lo, hi);
}

// ---- kernel 2: triangular C = X·Xᵀ (fp8 MFMA), row+col argmax epilogue -----
// Column-padded triangular schedule: every tile-column starts at a block
// index multiple of 8, so XCD (= blockIdx%8) always gets bi%8 == its id ->
// per-XCD A-band stays hot in its private L2 (R2's FETCH 3x regression fix).
// LDS 16B-granule g of row r holds global granule g^((r>>1)&3): all b64
// fragment reads are <=2-way bank aliased (free), staging stays
// global_load_lds-compatible.

__global__ __launch_bounds__(256) void gemm_argmax(
        const unsigned char* __restrict__ X, u64* __restrict__ best) {
    __shared__ unsigned char As[TILE * BK];
    __shared__ unsigned char Bs[TILE * BK];
    __shared__ u64 rmerge[TILE * 2];
    __shared__ u64 cmerge[TILE * 2];

    // decode padded-triangular block id: group g = bj>>3, per-column count 8(g+1)
    int l = blockIdx.x;
    int g = (int)((sqrtf((float)l * 0.125f + 0.25f) - 0.5f) * 0.5f);
    while (32 * (g + 1) * (g + 2) <= l) ++g;
    while (32 * g * (g + 1) > l) --g;
    int rrem = l - 32 * g * (g + 1);
    int cw   = 8 * (g + 1);
    int c    = rrem / cw;
    int bi   = rrem - c * cw;
    int bj   = 8 * g + c;
    if (bi > bj) return;                 // padding block
    const int m0 = bi * TILE;
    const int n0 = bj * TILE;
    const bool offdiag = (bi != bj);

    const int t    = threadIdx.x;
    const int lane = t & 63;
    const int w    = t >> 6;
    const int wm   = w >> 1, wn = w & 1;

    // staging: call covers 64 rows; thread t -> row t>>2, LDS granule t&3,
    // source granule (t&3)^((t>>3)&3)  [= (row>>1)&3 swizzle]
    const int rS   = t >> 2;
    const int gSrc = ((t & 3) ^ ((t >> 3) & 3)) * 16;
    const unsigned char* gA = X + (size_t)(m0 + rS) * D_DIM + gSrc;
    const unsigned char* gB = X + (size_t)(n0 + rS) * D_DIM + gSrc;
    unsigned char* lA = As + t * 16;
    unsigned char* lB = Bs + t * 16;

    f32x4 acc[4][4];
    #pragma unroll
    for (int mi = 0; mi < 4; mi++)
        #pragma unroll
        for (int ni = 0; ni < 4; ni++)
            acc[mi][ni] = (f32x4){0.f, 0.f, 0.f, 0.f};

    const int qr   = lane & 15;
    const int quad = lane >> 4;

    for (int k0 = 0; k0 < D_DIM; k0 += BK) {
        async16(lA,             gA + k0);
        async16(lA + 64 * BK,   gA + (size_t)64 * D_DIM + k0);
        async16(lB,             gB + k0);
        async16(lB + 64 * BK,   gB + (size_t)64 * D_DIM + k0);
        __syncthreads();

        #pragma unroll
        for (int ks = 0; ks < 2; ks++) {
            long av[4], bv[4];
            #pragma unroll
            for (int mi = 0; mi < 4; mi++) {
                int row = wm * 64 + mi * 16 + qr;
                int cl  = (ks * 4 + quad) ^ (qr & 6);
                av[mi] = *(const long*)(As + row * BK + cl * 8);
            }
            #pragma unroll
            for (int ni = 0; ni < 4; ni++) {
                int row = wn * 64 + ni * 16 + qr;
                int cl  = (ks * 4 + quad) ^ (qr & 6);
                bv[ni] = *(const long*)(Bs + row * BK + cl * 8);
            }
            #pragma unroll
            for (int mi = 0; mi < 4; mi++)
                #pragma unroll
                for (int ni = 0; ni < 4; ni++)
                    acc[mi][ni] = __builtin_amdgcn_mfma_f32_16x16x32_fp8_fp8(
                        av[mi], bv[ni], acc[mi][ni], 0, 0, 0);
        }
        __syncthreads();
    }

    // ---- row-side argmax over this tile's 128 cols (diag masked) ----------
    const int colg_base = n0 + wn * 64 + qr;
    #pragma unroll
    for (int mi = 0; mi < 4; mi++) {
        #pragma unroll
        for (int r = 0; r < 4; r++) {
            const int rowl = wm * 64 + mi * 16 + quad * 4 + r;
            const int rowg = m0 + rowl;
            u64 key = 0ull;
            #pragma unroll
            for (int ni = 0; ni < 4; ni++) {
                int colg = colg_base + ni * 16;
                if (colg == rowg) continue;
                float v = acc[mi][ni][r];
                u64 k = ((u64)fkey(v) << 32) | (u64)(0xFFFFFFFFu - (unsigned)colg);
                key = key > k ? key : k;
            }
            #pragma unroll
            for (int m = 1; m <= 8; m <<= 1) {
                u64 o = shfl_xor_u64(key, m);
                key = key > o ? key : o;
            }
            if (qr == 0) rmerge[rowl * 2 + wn] = key;
        }
    }

    // ---- col-side argmax (symmetry) ---------------------------------------
    if (offdiag) {
        #pragma unroll
        for (int ni = 0; ni < 4; ni++) {
            u64 key = 0ull;
            #pragma unroll
            for (int mi = 0; mi < 4; mi++) {
                #pragma unroll
                for (int r = 0; r < 4; r++) {
                    int rowg = m0 + wm * 64 + mi * 16 + quad * 4 + r;
                    float v = acc[mi][ni][r];
                    u64 k = ((u64)fkey(v) << 32) | (u64)(0xFFFFFFFFu - (unsigned)rowg);
                    key = key > k ? key : k;
                }
            }
            u64 o = shfl_xor_u64(key, 16); key = key > o ? key : o;
            o     = shfl_xor_u64(key, 32); key = key > o ? key : o;
            if (quad == 0) cmerge[(wn * 64 + ni * 16 + qr) * 2 + wm] = key;
        }
    }
    __syncthreads();
    if (t < TILE) {
        u64 a = rmerge[t * 2], b = rmerge[t * 2 + 1];
        u64 k = a > b ? a : b;
        atomicMax(&best[m0 + t], k);
        if (offdiag) {
            u64 ca = cmerge[t * 2], cb = cmerge[t * 2 + 1];
            u64 ck = ca > cb ? ca : cb;
            atomicMax(&best[n0 + t], ck);
        }
    }
}

// ---- kernel 3: exact fp32 distance + fused final reduce (ticket) -----------

__global__ __launch_bounds__(256) void neighbor_dist(
        const float* __restrict__ in, const float* __restrict__ inv_norm,
        const u64* __restrict__ best, float* __restrict__ acc,
        int* __restrict__ cnt, float* __restrict__ out, int B) {
    const int wave = threadIdx.x >> 6;
    const int row  = blockIdx.x * 4 + wave;
    const int lane = threadIdx.x & 63;
    u64 k   = best[row];
    int nbr = (int)(0xFFFFFFFFu - (unsigned)(k & 0xFFFFFFFFull));
    float ir  = inv_norm[row];
    float inb = inv_norm[nbr];
    const float4* rp = (const float4*)(in + (size_t)row * D_DIM) + lane * 2;
    const float4* np = (const float4*)(in + (size_t)nbr * D_DIM) + lane * 2;
    float4 r0 = rp[0], r1 = rp[1], n0 = np[0], n1 = np[1];
    float d0 = r0.x*ir - n0.x*inb + 1e-8f, d1 = r0.y*ir - n0.y*inb + 1e-8f;
    float d2 = r0.z*ir - n0.z*inb + 1e-8f, d3 = r0.w*ir - n0.w*inb + 1e-8f;
    float d4 = r1.x*ir - n1.x*inb + 1e-8f, d5 = r1.y*ir - n1.y*inb + 1e-8f;
    float d6 = r1.z*ir - n1.z*inb + 1e-8f, d7 = r1.w*ir - n1.w*inb + 1e-8f;
    float s = d0*d0 + d1*d1 + d2*d2 + d3*d3 + d4*d4 + d5*d5 + d6*d6 + d7*d7;
    #pragma unroll
    for (int m = 1; m <= 32; m <<= 1) s += __shfl_xor(s, m, 64);
    __shared__ float sb[4];
    if (lane == 0) sb[wave] = logf(sqrtf(s) + 1e-8f);
    __syncthreads();
    if (threadIdx.x == 0) {
        float partial = sb[0] + sb[1] + sb[2] + sb[3];
        atomicAdd(acc, partial);
        __threadfence();
        int done = atomicAdd(cnt, 1);
        if (done == gridDim.x - 1) {
            __threadfence();
            float tot = atomicAdd(acc, 0.0f);   // device-scope read
            out[0] = -tot / (float)B;
        }
    }
}

// ---- launch ----------------------------------------------------------------

extern "C" void kernel_launch(void* const* d_in, const int* in_sizes, int n_in,
                              void* d_out, int out_size, void* d_ws, size_t ws_size,
                              hipStream_t stream) {
    const float* in = (const float*)d_in[0];
    const int B  = in_sizes[0] / D_DIM;         // 8192
    const int nt = B / TILE;                    // 64
    const int ng = nt / 8;                      // 8 groups
    const int nblk = 32 * ng * (ng + 1);        // 2304 padded-triangular blocks

    char* w = (char*)d_ws;
    unsigned char* xb = (unsigned char*)w;                     // B*D fp8
    float*  invn = (float*)(w + (size_t)B * D_DIM);
    u64*    best = (u64*)(w + (size_t)B * D_DIM + (size_t)B * 4);
    float*  acc  = (float*)(w + (size_t)B * D_DIM + (size_t)B * 4 + (size_t)B * 8);
    int*    cnt  = (int*)(acc + 1);
    float*  out  = (float*)d_out;

    normalize_rows<<<B / 4, 256, 0, stream>>>(in, xb, invn, best, acc, cnt);
    gemm_argmax<<<nblk, 256, 0, stream>>>(xb, best);
    neighbor_dist<<<B / 4, 256, 0, stream>>>(in, invn, best, acc, cnt, out, B);
}

// Round 4
// 160.806 us; speedup vs baseline: 1.1976x; 1.1976x over previous
//
#include <hip/hip_runtime.h>
#include <hip/hip_bf16.h>
#include <math.h>

#define D_DIM 512
#define TILE  128
#define BK    128

typedef float f32x4 __attribute__((ext_vector_type(4)));
typedef int   i32x4v __attribute__((ext_vector_type(4)));
typedef int   i32x8v __attribute__((ext_vector_type(8)));
typedef unsigned long long u64;

// ---- helpers ---------------------------------------------------------------

__device__ inline unsigned int fkey(float f) {
    unsigned int u = __float_as_uint(f);
    return (u & 0x80000000u) ? ~u : (u | 0x80000000u);
}

__device__ inline u64 shfl_xor_u64(u64 x, int m) {
    int lo = __shfl_xor((int)(unsigned)(x & 0xFFFFFFFFull), m, 64);
    int hi = __shfl_xor((int)(unsigned)(x >> 32), m, 64);
    return ((u64)(unsigned)hi << 32) | (u64)(unsigned)lo;
}

__device__ inline void async16(unsigned char* lds, const unsigned char* g) {
    __builtin_amdgcn_global_load_lds(
        (const __attribute__((address_space(1))) void*)g,
        (__attribute__((address_space(3))) void*)lds,
        16, 0, 0);
}

// ---- kernel 1: row L2-normalize -> fp8 e4m3 (x8 scale), init best ----------

__global__ __launch_bounds__(256) void normalize_rows(
        const float* __restrict__ in, unsigned char* __restrict__ xb,
        float* __restrict__ inv_norm, u64* __restrict__ best) {
    const int row  = blockIdx.x * 4 + (threadIdx.x >> 6);
    const int lane = threadIdx.x & 63;
    const float4* rp = (const float4*)(in + (size_t)row * D_DIM) + lane * 2;
    float4 a = rp[0], b = rp[1];
    float s = a.x*a.x + a.y*a.y + a.z*a.z + a.w*a.w
            + b.x*b.x + b.y*b.y + b.z*b.z + b.w*b.w;
    #pragma unroll
    for (int m = 1; m <= 32; m <<= 1) s += __shfl_xor(s, m, 64);
    float inv = 1.0f / fmaxf(sqrtf(s), 1e-8f);
    if (lane == 0) {
        inv_norm[row] = inv;
        best[row] = 0ull;   // below any real packed key
    }
    float sc = inv * 8.0f;  // x8: dots scale by 64 (monotone), dodges subnormals
    int lo = __builtin_amdgcn_cvt_pk_fp8_f32(a.x*sc, a.y*sc, 0, false);
    lo     = __builtin_amdgcn_cvt_pk_fp8_f32(a.z*sc, a.w*sc, lo, true);
    int hi = __builtin_amdgcn_cvt_pk_fp8_f32(b.x*sc, b.y*sc, 0, false);
    hi     = __builtin_amdgcn_cvt_pk_fp8_f32(b.z*sc, b.w*sc, hi, true);
    ((int2*)(xb + (size_t)row * D_DIM))[lane] = make_int2(lo, hi);
}

// ---- kernel 2: triangular C = X·Xᵀ via MX-fp8 K=128 MFMA, argmax epilogue --
// Padded-triangular schedule (bi%8 == blockIdx%8 -> per-XCD L2 A-band, the
// R3-verified FETCH fix). LDS granule rotation slot(r,g)=8r+((g+r)&7): each
// lane's 32B fragment = two conflict-free ds_read_b128 (every 8-lane phase
// covers all 32 banks). Identity e8m0 scales (0x7F==x1) make the scaled
// MFMA a plain fp8 GEMM at 2x the non-scaled rate.

__global__ __launch_bounds__(256) void gemm_argmax(
        const unsigned char* __restrict__ X, u64* __restrict__ best) {
    __shared__ unsigned char As[TILE * BK];   // 16 KB
    __shared__ unsigned char Bs[TILE * BK];   // 16 KB
    __shared__ u64 rmerge[TILE * 2];
    __shared__ u64 cmerge[TILE * 2];

    // decode padded-triangular block id: group g = bj>>3, col width 8(g+1)
    int l = blockIdx.x;
    int g = (int)((sqrtf((float)l * 0.125f + 0.25f) - 0.5f) * 0.5f);
    while (32 * (g + 1) * (g + 2) <= l) ++g;
    while (32 * g * (g + 1) > l) --g;
    int rrem = l - 32 * g * (g + 1);
    int cw   = 8 * (g + 1);
    int c    = rrem / cw;
    int bi   = rrem - c * cw;
    int bj   = 8 * g + c;
    if (bi > bj) return;                 // padding block
    const int m0 = bi * TILE;
    const int n0 = bj * TILE;
    const bool offdiag = (bi != bj);

    const int t    = threadIdx.x;
    const int lane = t & 63;
    const int w    = t >> 6;
    const int wm   = w >> 1, wn = w & 1;
    const int qr   = lane & 15;
    const int quad = lane >> 4;

    f32x4 acc[4][4];
    #pragma unroll
    for (int mi = 0; mi < 4; mi++)
        #pragma unroll
        for (int ni = 0; ni < 4; ni++)
            acc[mi][ni] = (f32x4){0.f, 0.f, 0.f, 0.f};

    // staging source (per call c): LDS granule L=c*256+t holds global
    // (row L>>3, granule ((L&7)-(row&7))&7) of the current 128B K-chunk.
    int   sRow[4], sOff[4];
    #pragma unroll
    for (int cc = 0; cc < 4; cc++) {
        int L = cc * 256 + t;
        int r = L >> 3;
        int gg = ((L & 7) - (r & 7)) & 7;
        sRow[cc] = r;
        sOff[cc] = gg * 16;
    }

    for (int k0 = 0; k0 < D_DIM; k0 += BK) {
        #pragma unroll
        for (int cc = 0; cc < 4; cc++) {
            const unsigned char* srcA =
                X + (size_t)(m0 + sRow[cc]) * D_DIM + k0 + sOff[cc];
            const unsigned char* srcB =
                X + (size_t)(n0 + sRow[cc]) * D_DIM + k0 + sOff[cc];
            async16(As + cc * 4096 + t * 16, srcA);
            async16(Bs + cc * 4096 + t * 16, srcB);
        }
        __syncthreads();

        i32x8v av[4], bv[4];
        #pragma unroll
        for (int mi = 0; mi < 4; mi++) {
            int row = wm * 64 + mi * 16 + qr;
            int s0  = row * 8 + ((2 * quad + row) & 7);
            int s1  = row * 8 + ((2 * quad + 1 + row) & 7);
            i32x4v lo = *(const i32x4v*)(As + s0 * 16);
            i32x4v hi = *(const i32x4v*)(As + s1 * 16);
            av[mi] = __builtin_shufflevector(lo, hi, 0, 1, 2, 3, 4, 5, 6, 7);
        }
        #pragma unroll
        for (int ni = 0; ni < 4; ni++) {
            int row = wn * 64 + ni * 16 + qr;
            int s0  = row * 8 + ((2 * quad + row) & 7);
            int s1  = row * 8 + ((2 * quad + 1 + row) & 7);
            i32x4v lo = *(const i32x4v*)(Bs + s0 * 16);
            i32x4v hi = *(const i32x4v*)(Bs + s1 * 16);
            bv[ni] = __builtin_shufflevector(lo, hi, 0, 1, 2, 3, 4, 5, 6, 7);
        }
        #pragma unroll
        for (int mi = 0; mi < 4; mi++)
            #pragma unroll
            for (int ni = 0; ni < 4; ni++)
                acc[mi][ni] = __builtin_amdgcn_mfma_scale_f32_16x16x128_f8f6f4(
                    av[mi], bv[ni], acc[mi][ni],
                    0, 0,                      // cbsz=A fmt fp8, blgp=B fmt fp8
                    0, 0x7F7F7F7F,             // opsel_a, scale_a (e8m0 1.0)
                    0, 0x7F7F7F7F);            // opsel_b, scale_b
        __syncthreads();
    }

    // ---- row-side argmax over this tile's 128 cols (diag masked) ----------
    const int colg_base = n0 + wn * 64 + qr;
    #pragma unroll
    for (int mi = 0; mi < 4; mi++) {
        #pragma unroll
        for (int r = 0; r < 4; r++) {
            const int rowl = wm * 64 + mi * 16 + quad * 4 + r;
            const int rowg = m0 + rowl;
            u64 key = 0ull;
            #pragma unroll
            for (int ni = 0; ni < 4; ni++) {
                int colg = colg_base + ni * 16;
                if (colg == rowg) continue;
                float v = acc[mi][ni][r];
                u64 k = ((u64)fkey(v) << 32) | (u64)(0xFFFFFFFFu - (unsigned)colg);
                key = key > k ? key : k;
            }
            #pragma unroll
            for (int m = 1; m <= 8; m <<= 1) {
                u64 o = shfl_xor_u64(key, m);
                key = key > o ? key : o;
            }
            if (qr == 0) rmerge[rowl * 2 + wn] = key;
        }
    }

    // ---- col-side argmax (symmetry) ---------------------------------------
    if (offdiag) {
        #pragma unroll
        for (int ni = 0; ni < 4; ni++) {
            u64 key = 0ull;
            #pragma unroll
            for (int mi = 0; mi < 4; mi++) {
                #pragma unroll
                for (int r = 0; r < 4; r++) {
                    int rowg = m0 + wm * 64 + mi * 16 + quad * 4 + r;
                    float v = acc[mi][ni][r];
                    u64 k = ((u64)fkey(v) << 32) | (u64)(0xFFFFFFFFu - (unsigned)rowg);
                    key = key > k ? key : k;
                }
            }
            u64 o = shfl_xor_u64(key, 16); key = key > o ? key : o;
            o     = shfl_xor_u64(key, 32); key = key > o ? key : o;
            if (quad == 0) cmerge[(wn * 64 + ni * 16 + qr) * 2 + wm] = key;
        }
    }
    __syncthreads();
    if (t < TILE) {
        u64 a = rmerge[t * 2], b = rmerge[t * 2 + 1];
        u64 k = a > b ? a : b;
        atomicMax(&best[m0 + t], k);
        if (offdiag) {
            u64 ca = cmerge[t * 2], cb = cmerge[t * 2 + 1];
            u64 ck = ca > cb ? ca : cb;
            atomicMax(&best[n0 + t], ck);
        }
    }
}

// ---- kernel 3: exact fp32 distance to chosen neighbor (1 wave/row) ---------

__global__ __launch_bounds__(256) void neighbor_dist(
        const float* __restrict__ in, const float* __restrict__ inv_norm,
        const u64* __restrict__ best, float* __restrict__ rowval) {
    const int row  = blockIdx.x * 4 + (threadIdx.x >> 6);
    const int lane = threadIdx.x & 63;
    u64 k   = best[row];
    int nbr = (int)(0xFFFFFFFFu - (unsigned)(k & 0xFFFFFFFFull));
    float ir  = inv_norm[row];
    float inb = inv_norm[nbr];
    const float4* rp = (const float4*)(in + (size_t)row * D_DIM) + lane * 2;
    const float4* np = (const float4*)(in + (size_t)nbr * D_DIM) + lane * 2;
    float4 r0 = rp[0], r1 = rp[1], n0 = np[0], n1 = np[1];
    float d0 = r0.x*ir - n0.x*inb + 1e-8f, d1 = r0.y*ir - n0.y*inb + 1e-8f;
    float d2 = r0.z*ir - n0.z*inb + 1e-8f, d3 = r0.w*ir - n0.w*inb + 1e-8f;
    float d4 = r1.x*ir - n1.x*inb + 1e-8f, d5 = r1.y*ir - n1.y*inb + 1e-8f;
    float d6 = r1.z*ir - n1.z*inb + 1e-8f, d7 = r1.w*ir - n1.w*inb + 1e-8f;
    float s = d0*d0 + d1*d1 + d2*d2 + d3*d3 + d4*d4 + d5*d5 + d6*d6 + d7*d7;
    #pragma unroll
    for (int m = 1; m <= 32; m <<= 1) s += __shfl_xor(s, m, 64);
    if (lane == 0) rowval[row] = logf(sqrtf(s) + 1e-8f);
}

// ---- kernel 4: final mean --------------------------------------------------

__global__ __launch_bounds__(256) void final_reduce(
        const float* __restrict__ rowval, float* __restrict__ out, int B) {
    int t = threadIdx.x;
    const float4* rv = (const float4*)rowval;
    float s = 0.f;
    for (int i = t; i < B / 4; i += 256) {
        float4 v = rv[i];
        s += v.x + v.y + v.z + v.w;
    }
    #pragma unroll
    for (int m = 1; m <= 32; m <<= 1) s += __shfl_xor(s, m, 64);
    __shared__ float sb[4];
    if ((t & 63) == 0) sb[t >> 6] = s;
    __syncthreads();
    if (t == 0) out[0] = -(sb[0] + sb[1] + sb[2] + sb[3]) / (float)B;
}

// ---- launch ----------------------------------------------------------------

extern "C" void kernel_launch(void* const* d_in, const int* in_sizes, int n_in,
                              void* d_out, int out_size, void* d_ws, size_t ws_size,
                              hipStream_t stream) {
    const float* in = (const float*)d_in[0];
    const int B  = in_sizes[0] / D_DIM;         // 8192
    const int nt = B / TILE;                    // 64
    const int ng = nt / 8;                      // 8 groups
    const int nblk = 32 * ng * (ng + 1);        // 2304 padded-triangular blocks

    char* w = (char*)d_ws;
    unsigned char* xb = (unsigned char*)w;                     // B*D fp8
    float*  invn   = (float*)(w + (size_t)B * D_DIM);
    u64*    best   = (u64*)(w + (size_t)B * D_DIM + (size_t)B * 4);
    float*  rowval = (float*)(w + (size_t)B * D_DIM + (size_t)B * 4 + (size_t)B * 8);
    float*  out    = (float*)d_out;

    normalize_rows<<<B / 4, 256, 0, stream>>>(in, xb, invn, best);
    gemm_argmax<<<nblk, 256, 0, stream>>>(xb, best);
    neighbor_dist<<<B / 4, 256, 0, stream>>>(in, invn, best, rowval);
    final_reduce<<<1, 256, 0, stream>>>(rowval, out, B);
}